// Round 1
// baseline (570.354 us; speedup 1.0000x reference)
//
#include <hip/hip_runtime.h>
#include <hip/hip_bf16.h>

#define N_TOK 4096
#define CCH   512
// CI = 64, B = 8

using f32x4  = __attribute__((ext_vector_type(4))) float;
using bf16x8 = __attribute__((ext_vector_type(8))) short;

__device__ __forceinline__ short f2bf(float f) {
  __hip_bfloat16 h = __float2bfloat16(f);
  return __builtin_bit_cast(short, h);
}

__device__ __forceinline__ f32x4 mfma16(bf16x8 a, bf16x8 b, f32x4 c) {
  return __builtin_amdgcn_mfma_f32_16x16x32_bf16(a, b, c, 0, 0, 0);
}

// ---- LDS tile helpers: tiles are (rows x 64 bf16) = 128B rows.
// XOR swizzle on 16B granules: phys_granule = logical_granule ^ (row & 7).
// Makes the per-lane column-slice frag reads (16 lanes, rows stride 128B) ~2-way.
__device__ __forceinline__ void stage_tile(short* lds, const short* src, int src_stride,
                                           int granules, int tid, int nthr) {
  for (int g = tid; g < granules; g += nthr) {
    int r = g >> 3, c16 = g & 7;
    bf16x8 v = *(const bf16x8*)(src + r * src_stride + c16 * 8);
    *(bf16x8*)(lds + r * 64 + ((c16 ^ (r & 7)) * 8)) = v;
  }
}

// frag read: lane holds row = row0 + (lane&15), k bytes at granule ks*4 + (lane>>4)
__device__ __forceinline__ bf16x8 read_frag(const short* lds, int row0, int ks, int lane) {
  int r = row0 + (lane & 15);
  int c16 = ks * 4 + (lane >> 4);
  return *(const bf16x8*)(lds + r * 64 + ((c16 ^ (r & 7)) * 8));
}

// ---------------- weight conversion ----------------
__global__ void k_conv_w(const float* wq, const float* wk, const float* wv,
                         const float* bq, const float* bk,
                         short* wqk_bf, short* wv_bf, float* bqk) {
  int idx = blockIdx.x * blockDim.x + threadIdx.x;
  int stride = gridDim.x * blockDim.x;
  const int n1 = 128 * 512;
  const int n2 = 512 * 512;
  for (int i = idx; i < n1; i += stride) {
    int d = i >> 9, c = i & 511;
    float v = (d < 64) ? wq[d * 512 + c] : wk[(d - 64) * 512 + c];
    wqk_bf[i] = f2bf(v);
  }
  for (int i = idx; i < n2; i += stride) wv_bf[i] = f2bf(wv[i]);
  if (idx < 128) bqk[idx] = (idx < 64) ? bq[idx] : bk[idx - 64];
}

// ---------------- x (B,C,N) f32 -> xT (B,N,C) bf16 ----------------
__global__ __launch_bounds__(256) void k_transpose_x(const float* x, short* xT) {
  __shared__ float tile[64][65];
  int b = blockIdx.z, c0 = blockIdx.y * 64, n0 = blockIdx.x * 64;
  int tid = threadIdx.x;
  int col = tid & 63, rowb = tid >> 6;
  for (int r = rowb; r < 64; r += 4)
    tile[r][col] = x[((long)b * CCH + c0 + r) * N_TOK + n0 + col];
  __syncthreads();
  for (int r = rowb; r < 64; r += 4)
    xT[((long)b * N_TOK + n0 + r) * CCH + c0 + col] = f2bf(tile[col][r]);
}

// ---------------- generic NT GEMM: C[m,n] = A[m,:] . Bt[n,:] (+bias), bf16 out ----
// A row-major (M x K), Bt row-major (N x K). 128x128 tile, 4 waves (2x2), K step 64.
__global__ __launch_bounds__(256) void k_gemm_nt(
    const short* A, long long Ab, const short* Bt, long long Bb,
    short* out, long long Ob, int out_stride,
    const float* bias, int bias_row, int K) {
  __shared__ short Al[128 * 64], Bl[128 * 64];
  int b = blockIdx.z;
  int m0 = blockIdx.y * 128, n0 = blockIdx.x * 128;
  int tid = threadIdx.x, lane = tid & 63, w = tid >> 6;
  int wm = w >> 1, wn = w & 1;
  const short* Ap = A + b * Ab + (long long)m0 * K;
  const short* Bp = Bt + b * Bb + (long long)n0 * K;
  f32x4 acc[4][4] = {};
  for (int kt = 0; kt < K; kt += 64) {
    __syncthreads();
    stage_tile(Al, Ap + kt, K, 1024, tid, 256);
    stage_tile(Bl, Bp + kt, K, 1024, tid, 256);
    __syncthreads();
    for (int ks = 0; ks < 2; ++ks) {
      bf16x8 af[4], bfr[4];
      for (int i = 0; i < 4; ++i) af[i] = read_frag(Al, wm * 64 + i * 16, ks, lane);
      for (int i = 0; i < 4; ++i) bfr[i] = read_frag(Bl, wn * 64 + i * 16, ks, lane);
      for (int mf = 0; mf < 4; ++mf)
        for (int nf = 0; nf < 4; ++nf)
          acc[mf][nf] = mfma16(af[mf], bfr[nf], acc[mf][nf]);
    }
  }
  for (int mf = 0; mf < 4; ++mf)
    for (int nf = 0; nf < 4; ++nf)
      for (int t = 0; t < 4; ++t) {
        int m = m0 + wm * 64 + mf * 16 + (lane >> 4) * 4 + t;
        int n = n0 + wn * 64 + nf * 16 + (lane & 15);
        float v = acc[mf][nf][t];
        v += bias_row ? bias[m] : bias[n];
        out[b * Ob + (long long)m * out_stride + n] = f2bf(v);
      }
}

// ---------------- pass A: Zlog[b,i] = ln( sum_j exp(e[i,j]) ) ----------------
// qkT layout: (B, N, 128) bf16, cols 0-63 = q, 64-127 = k.
__global__ __launch_bounds__(256) void k_passA(const short* qkT, float* Zlog) {
  __shared__ short ql[64 * 64], kl[128 * 64];
  __shared__ float zbuf[4][64];
  int b = blockIdx.y, i0 = blockIdx.x * 64;
  int tid = threadIdx.x, lane = tid & 63, w = tid >> 6;
  stage_tile(ql, qkT + ((long long)b * N_TOK + i0) * 128, 128, 512, tid, 256);
  __syncthreads();
  bf16x8 qfr[4][2];
  for (int af = 0; af < 4; ++af)
    for (int ds = 0; ds < 2; ++ds)
      qfr[af][ds] = read_frag(ql, af * 16, ds, lane);
  float zacc[4][4] = {};
  for (int jt = 0; jt < 32; ++jt) {
    int j0 = jt * 128;
    __syncthreads();
    stage_tile(kl, qkT + ((long long)b * N_TOK + j0) * 128 + 64, 128, 1024, tid, 256);
    __syncthreads();
    f32x4 sacc[4][2] = {};
    for (int ds = 0; ds < 2; ++ds) {
      bf16x8 kf[2];
      for (int jn = 0; jn < 2; ++jn) kf[jn] = read_frag(kl, w * 32 + jn * 16, ds, lane);
      for (int af = 0; af < 4; ++af)
        for (int jn = 0; jn < 2; ++jn)
          sacc[af][jn] = mfma16(qfr[af][ds], kf[jn], sacc[af][jn]);
    }
    for (int af = 0; af < 4; ++af)
      for (int jn = 0; jn < 2; ++jn)
        for (int t = 0; t < 4; ++t)
          zacc[af][t] += __expf(sacc[af][jn][t]);
  }
  // reduce over j-columns held across lanes 0..15 of each 16-lane group
  for (int af = 0; af < 4; ++af)
    for (int t = 0; t < 4; ++t) {
      float v = zacc[af][t];
      v += __shfl_xor(v, 1); v += __shfl_xor(v, 2);
      v += __shfl_xor(v, 4); v += __shfl_xor(v, 8);
      if ((lane & 15) == 0) zbuf[w][af * 16 + (lane >> 4) * 4 + t] = v;
    }
  __syncthreads();
  if (tid < 64)
    Zlog[(long long)b * N_TOK + i0 + tid] =
        __logf(zbuf[0][tid] + zbuf[1][tid] + zbuf[2][tid] + zbuf[3][tid]);
}

// ---------------- pass B: out[b,c,j] = gamma * sum_i v[c,i]*exp(e[i,j]-Zlog[i]) + x
// block: j-tile 128 (x), c-tile 128 (y), batch (z). 4 waves.
__global__ __launch_bounds__(256) void k_passB(
    const short* qkT, const short* v_bf, const float* Zlog,
    const float* x, const float* gamma_p, float* out) {
  __shared__ short ql[64 * 64];   // q rows i (64) x d (64)
  __shared__ short vl[128 * 64];  // v rows c (128) x i (64)
  __shared__ short pl[128 * 64];  // P rows j (128) x i (64)
  int b = blockIdx.z, j0 = blockIdx.x * 128, c0 = blockIdx.y * 128;
  int tid = threadIdx.x, lane = tid & 63, w = tid >> 6;
  float gamma = *gamma_p;
  // hoist kT A-frags: wave w owns S rows j in [w*32, w*32+32)
  bf16x8 kfr[2][2];
  for (int jj = 0; jj < 2; ++jj)
    for (int ds = 0; ds < 2; ++ds) {
      int j = j0 + w * 32 + jj * 16 + (lane & 15);
      const short* p = qkT + ((long long)b * N_TOK + j) * 128 + 64 + ds * 32 + (lane >> 4) * 8;
      kfr[jj][ds] = *(const bf16x8*)p;
    }
  int wc = w >> 1, wj = w & 1;
  f32x4 oacc[4][4] = {};
  for (int it = 0; it < 64; ++it) {
    int i0 = it * 64;
    __syncthreads();  // prev iter's LDS reads complete
    stage_tile(ql, qkT + ((long long)b * N_TOK + i0) * 128, 128, 512, tid, 256);
    stage_tile(vl, v_bf + ((long long)b * CCH + c0) * N_TOK + i0, N_TOK, 1024, tid, 256);
    float c2[4];
    for (int f = 0; f < 4; ++f)
      c2[f] = Zlog[(long long)b * N_TOK + i0 + f * 16 + (lane & 15)];
    __syncthreads();  // staging visible
    // S[j,i] = e[i,j], rows j (wave-split), cols i (64)
    f32x4 sacc[2][4] = {};
    for (int ds = 0; ds < 2; ++ds) {
      bf16x8 qf[4];
      for (int f = 0; f < 4; ++f) qf[f] = read_frag(ql, f * 16, ds, lane);
      for (int jj = 0; jj < 2; ++jj)
        for (int f = 0; f < 4; ++f)
          sacc[jj][f] = mfma16(kfr[jj][ds], qf[f], sacc[jj][f]);
    }
    // P = exp(S - lnZ[i]) -> bf16 -> pl (swizzled scalar writes)
    for (int jj = 0; jj < 2; ++jj)
      for (int f = 0; f < 4; ++f)
        for (int t = 0; t < 4; ++t) {
          int jr = w * 32 + jj * 16 + (lane >> 4) * 4 + t;
          int ic = f * 16 + (lane & 15);
          float p = __expf(sacc[jj][f][t] - c2[f]);
          pl[jr * 64 + (((ic >> 3) ^ (jr & 7)) * 8) + (ic & 7)] = f2bf(p);
        }
    __syncthreads();  // P visible
    // O'[c,j] += V[c,i-tile] . P[j,i-tile]^T : wave owns (wc*64 c) x (wj*64 j)
    for (int ks = 0; ks < 2; ++ks) {
      bf16x8 vf[4], pf[4];
      for (int cf = 0; cf < 4; ++cf) vf[cf] = read_frag(vl, wc * 64 + cf * 16, ks, lane);
      for (int jn = 0; jn < 4; ++jn) pf[jn] = read_frag(pl, wj * 64 + jn * 16, ks, lane);
      for (int cf = 0; cf < 4; ++cf)
        for (int jn = 0; jn < 4; ++jn)
          oacc[cf][jn] = mfma16(vf[cf], pf[jn], oacc[cf][jn]);
    }
  }
  // fused epilogue: out = gamma*O' + x (coalesced 16-lane f32 runs)
  for (int cf = 0; cf < 4; ++cf)
    for (int jn = 0; jn < 4; ++jn)
      for (int t = 0; t < 4; ++t) {
        int c = c0 + wc * 64 + cf * 16 + (lane >> 4) * 4 + t;
        int j = j0 + wj * 64 + jn * 16 + (lane & 15);
        long long idx = ((long long)b * CCH + c) * N_TOK + j;
        out[idx] = gamma * oacc[cf][jn][t] + x[idx];
      }
}

extern "C" void kernel_launch(void* const* d_in, const int* in_sizes, int n_in,
                              void* d_out, int out_size, void* d_ws, size_t ws_size,
                              hipStream_t stream) {
  const float* x     = (const float*)d_in[0];
  const float* wq    = (const float*)d_in[1];
  const float* bq    = (const float*)d_in[2];
  const float* wk    = (const float*)d_in[3];
  const float* bk    = (const float*)d_in[4];
  const float* wv    = (const float*)d_in[5];
  const float* bv    = (const float*)d_in[6];
  const float* gamma = (const float*)d_in[7];
  float* out = (float*)d_out;
  char* ws = (char*)d_ws;

  // workspace layout (bytes)
  short* xT     = (short*)(ws);                 // 8*4096*512*2  = 33554432
  short* qkT    = (short*)(ws + 33554432);      // 8*4096*128*2  =  8388608
  short* v_bf   = (short*)(ws + 41943040);      // 8*512*4096*2  = 33554432
  float* Zlog   = (float*)(ws + 75497472);      // 8*4096*4      =   131072
  short* wqk_bf = (short*)(ws + 75628544);      // 128*512*2     =   131072
  short* wv_bf  = (short*)(ws + 75759616);      // 512*512*2     =   524288
  float* bqk    = (float*)(ws + 76283904);      // 128*4         =      512

  k_conv_w<<<dim3(256), dim3(256), 0, stream>>>(wq, wk, wv, bq, bk, wqk_bf, wv_bf, bqk);
  k_transpose_x<<<dim3(64, 8, 8), dim3(256), 0, stream>>>(x, xT);
  // qkT[b,n,0:128] = xT[b,n,:] @ [wq;wk]^T + [bq;bk]
  k_gemm_nt<<<dim3(1, 32, 8), dim3(256), 0, stream>>>(
      xT, (long long)4096 * 512, wqk_bf, (long long)0,
      qkT, (long long)4096 * 128, 128, bqk, 0, 512);
  // v_bf[b,c,n] = wv[c,:] @ xT[b,n,:] + bv[c]
  k_gemm_nt<<<dim3(32, 4, 8), dim3(256), 0, stream>>>(
      wv_bf, (long long)0, xT, (long long)4096 * 512,
      v_bf, (long long)512 * 4096, 4096, bv, 1, 512);
  k_passA<<<dim3(64, 8), dim3(256), 0, stream>>>(qkT, Zlog);
  k_passB<<<dim3(32, 4, 8), dim3(256), 0, stream>>>(qkT, v_bf, Zlog, x, gamma, out);
}

// Round 3
// 360.065 us; speedup vs baseline: 1.5840x; 1.5840x over previous
//
#include <hip/hip_runtime.h>
#include <hip/hip_bf16.h>

#define N_TOK 4096
#define CCH   512
// CI = 64, B = 8

using f32x4  = __attribute__((ext_vector_type(4))) float;
using f32x16 = __attribute__((ext_vector_type(16))) float;
using bf16x4 = __attribute__((ext_vector_type(4))) short;
using bf16x8 = __attribute__((ext_vector_type(8))) short;

__device__ __forceinline__ short f2bf(float f) {
  __hip_bfloat16 h = __float2bfloat16(f);
  return __builtin_bit_cast(short, h);
}

__device__ __forceinline__ f32x4 mfma16(bf16x8 a, bf16x8 b, f32x4 c) {
  return __builtin_amdgcn_mfma_f32_16x16x32_bf16(a, b, c, 0, 0, 0);
}
__device__ __forceinline__ f32x16 mfma32(bf16x8 a, bf16x8 b, f32x16 c) {
  return __builtin_amdgcn_mfma_f32_32x32x16_bf16(a, b, c, 0, 0, 0);
}

__device__ __forceinline__ void gload16(const void* g, void* l) {
  __builtin_amdgcn_global_load_lds(
      (const __attribute__((address_space(1))) void*)g,
      (__attribute__((address_space(3))) void*)l, 16, 0, 0);
}

// ---- LDS tile helpers: tiles are (rows x 64 bf16) = 128B rows.
// XOR swizzle on 16B granules: phys_granule = logical_granule ^ (row & 7).
__device__ __forceinline__ void stage_tile(short* lds, const short* src, int src_stride,
                                           int granules, int tid, int nthr) {
  for (int g = tid; g < granules; g += nthr) {
    int r = g >> 3, c16 = g & 7;
    bf16x8 v = *(const bf16x8*)(src + r * src_stride + c16 * 8);
    *(bf16x8*)(lds + r * 64 + ((c16 ^ (r & 7)) * 8)) = v;
  }
}

// frag read (16x16 path): lane holds row = row0 + (lane&15), granule ks*4 + (lane>>4)
__device__ __forceinline__ bf16x8 read_frag(const short* lds, int row0, int ks, int lane) {
  int r = row0 + (lane & 15);
  int c16 = ks * 4 + (lane >> 4);
  return *(const bf16x8*)(lds + r * 64 + ((c16 ^ (r & 7)) * 8));
}

// ---------------- weight conversion ----------------
__global__ void k_conv_w(const float* wq, const float* wk, const float* wv,
                         const float* bq, const float* bk,
                         short* wqk_bf, short* wv_bf, float* bqk) {
  int idx = blockIdx.x * blockDim.x + threadIdx.x;
  int stride = gridDim.x * blockDim.x;
  const int n1 = 128 * 512;
  const int n2 = 512 * 512;
  for (int i = idx; i < n1; i += stride) {
    int d = i >> 9, c = i & 511;
    float v = (d < 64) ? wq[d * 512 + c] : wk[(d - 64) * 512 + c];
    wqk_bf[i] = f2bf(v);
  }
  for (int i = idx; i < n2; i += stride) wv_bf[i] = f2bf(wv[i]);
  if (idx < 128) bqk[idx] = (idx < 64) ? bq[idx] : bk[idx - 64];
}

// ---------------- x (B,C,N) f32 -> xT (B,N,C) bf16 ----------------
__global__ __launch_bounds__(256) void k_transpose_x(const float* x, short* xT) {
  __shared__ float tile[64][65];
  int b = blockIdx.z, c0 = blockIdx.y * 64, n0 = blockIdx.x * 64;
  int tid = threadIdx.x;
  int col = tid & 63, rowb = tid >> 6;
  for (int r = rowb; r < 64; r += 4)
    tile[r][col] = x[((long)b * CCH + c0 + r) * N_TOK + n0 + col];
  __syncthreads();
  for (int r = rowb; r < 64; r += 4)
    xT[((long)b * N_TOK + n0 + r) * CCH + c0 + col] = f2bf(tile[col][r]);
}

// ---------------- generic NT GEMM: C[m,n] = A[m,:] . Bt[n,:] (+bias)(*colscale[b,n]) ----
__global__ __launch_bounds__(256) void k_gemm_nt(
    const short* A, long long Ab, const short* Bt, long long Bb,
    short* out, long long Ob, int out_stride,
    const float* bias, int bias_row, const float* colscale, long long cs_stride, int K) {
  __shared__ short Al[128 * 64], Bl[128 * 64];
  int b = blockIdx.z;
  int m0 = blockIdx.y * 128, n0 = blockIdx.x * 128;
  int tid = threadIdx.x, lane = tid & 63, w = tid >> 6;
  int wm = w >> 1, wn = w & 1;
  const short* Ap = A + b * Ab + (long long)m0 * K;
  const short* Bp = Bt + b * Bb + (long long)n0 * K;
  f32x4 acc[4][4] = {};
  for (int kt = 0; kt < K; kt += 64) {
    __syncthreads();
    stage_tile(Al, Ap + kt, K, 1024, tid, 256);
    stage_tile(Bl, Bp + kt, K, 1024, tid, 256);
    __syncthreads();
    for (int ks = 0; ks < 2; ++ks) {
      bf16x8 af[4], bfr[4];
      for (int i = 0; i < 4; ++i) af[i] = read_frag(Al, wm * 64 + i * 16, ks, lane);
      for (int i = 0; i < 4; ++i) bfr[i] = read_frag(Bl, wn * 64 + i * 16, ks, lane);
      for (int mf = 0; mf < 4; ++mf)
        for (int nf = 0; nf < 4; ++nf)
          acc[mf][nf] = mfma16(af[mf], bfr[nf], acc[mf][nf]);
    }
  }
  for (int mf = 0; mf < 4; ++mf)
    for (int nf = 0; nf < 4; ++nf)
      for (int t = 0; t < 4; ++t) {
        int m = m0 + wm * 64 + mf * 16 + (lane >> 4) * 4 + t;
        int n = n0 + wn * 64 + nf * 16 + (lane & 15);
        float v = acc[mf][nf][t];
        v += bias_row ? bias[m] : bias[n];
        if (colscale) v *= colscale[b * cs_stride + n];  // batch-aware (round-2 bug fix)
        out[b * Ob + (long long)m * out_stride + n] = f2bf(v);
      }
}

// ---------------- pass A: Zinv[b,i] = 1 / sum_j exp(e[i,j]) ----------------
// qkT layout: (B, N, 128) bf16, cols 0-63 = q, 64-127 = k.
__global__ __launch_bounds__(256) void k_passA(const short* qkT, float* Zinv) {
  __shared__ short ql[64 * 64], kl[128 * 64];
  __shared__ float zbuf[4][64];
  int b = blockIdx.y, i0 = blockIdx.x * 64;
  int tid = threadIdx.x, lane = tid & 63, w = tid >> 6;
  stage_tile(ql, qkT + ((long long)b * N_TOK + i0) * 128, 128, 512, tid, 256);
  __syncthreads();
  bf16x8 qfr[4][2];
  for (int af = 0; af < 4; ++af)
    for (int ds = 0; ds < 2; ++ds)
      qfr[af][ds] = read_frag(ql, af * 16, ds, lane);
  float zacc[4][4] = {};
  for (int jt = 0; jt < 32; ++jt) {
    int j0 = jt * 128;
    __syncthreads();
    stage_tile(kl, qkT + ((long long)b * N_TOK + j0) * 128 + 64, 128, 1024, tid, 256);
    __syncthreads();
    f32x4 sacc[4][2] = {};
    for (int ds = 0; ds < 2; ++ds) {
      bf16x8 kf[2];
      for (int jn = 0; jn < 2; ++jn) kf[jn] = read_frag(kl, w * 32 + jn * 16, ds, lane);
      for (int af = 0; af < 4; ++af)
        for (int jn = 0; jn < 2; ++jn)
          sacc[af][jn] = mfma16(qfr[af][ds], kf[jn], sacc[af][jn]);
    }
    for (int af = 0; af < 4; ++af)
      for (int jn = 0; jn < 2; ++jn)
        for (int t = 0; t < 4; ++t)
          zacc[af][t] += __expf(sacc[af][jn][t]);
  }
  for (int af = 0; af < 4; ++af)
    for (int t = 0; t < 4; ++t) {
      float v = zacc[af][t];
      v += __shfl_xor(v, 1); v += __shfl_xor(v, 2);
      v += __shfl_xor(v, 4); v += __shfl_xor(v, 8);
      if ((lane & 15) == 0) zbuf[w][af * 16 + (lane >> 4) * 4 + t] = v;
    }
  __syncthreads();
  if (tid < 64) {
    float z = zbuf[0][tid] + zbuf[1][tid] + zbuf[2][tid] + zbuf[3][tid];
    Zinv[(long long)b * N_TOK + i0 + tid] = 1.0f / z;
  }
}

// ---------------- pass B: out[b,c,j] = gamma * sum_i Vs[c,i]*exp(e[i,j]) + x
// Vs = V * Zinv (pre-scaled in GEMM2). 256c x 256j tile, 8 waves, 32x32x16 MFMA.
// Double-buffered global_load_lds staging, 2 raw barriers per i-step.
__global__ __launch_bounds__(512, 2) void k_passB(
    const short* __restrict__ qkT, const short* __restrict__ v_bf,
    const float* __restrict__ x, const float* __restrict__ gamma_p,
    float* __restrict__ out) {
  __shared__ short ql[2][64 * 64];    // q rows i (64) x d (64)       16 KB
  __shared__ short vl[2][256 * 64];   // Vs rows c (256) x i (64)     64 KB
  __shared__ short pl[2][256 * 64];   // P rows j (256) x i (64)      64 KB
  const int b = blockIdx.z;
  const int j0 = blockIdx.x * 256;
  const int c0 = blockIdx.y * 256;
  const int tid = threadIdx.x;
  const int lane = tid & 63, w = tid >> 6;
  const int l31 = lane & 31, hi = lane >> 5;
  const int wc = w >> 2, wj = w & 3;  // PV: 2 c-groups x 4 j-groups
  const float gamma = *gamma_p;

  // hoisted K B-frags: wave w owns S'-cols j in [j0+w*32, +32)
  bf16x8 kf[4];
  {
    const short* kp = qkT + ((long long)b * N_TOK + j0 + w * 32 + l31) * 128 + 64 + hi * 8;
#pragma unroll
    for (int ks = 0; ks < 4; ++ks) kf[ks] = *(const bf16x8*)(kp + ks * 16);
  }

  // per-lane pre-swizzled staging source pointers (LDS dest stays linear)
  const int qidx = w * 64 + lane;  // 0..511 granules of ql
  const int qr = qidx >> 3, qg = qidx & 7;
  const short* qsrc0 = qkT + ((long long)b * N_TOK + qr) * 128 + ((qg ^ (qr & 7)) * 8);
  const short* vsrc0[4];
#pragma unroll
  for (int q = 0; q < 4; ++q) {
    int idx = (w * 4 + q) * 64 + lane;  // 0..2047 granules of vl
    int r = idx >> 3, g = idx & 7;
    vsrc0[q] = v_bf + ((long long)(b * CCH + c0 + r)) * N_TOK + ((g ^ (r & 7)) * 8);
  }

  f32x16 oacc[4][2] = {};

#define STAGE(buf, step)                                            \
  do {                                                              \
    gload16(qsrc0 + (long long)(step) * 64 * 128, &ql[buf][w * 512]); \
    _Pragma("unroll")                                               \
    for (int q = 0; q < 4; ++q)                                     \
      gload16(vsrc0[q] + (step) * 64, &vl[buf][(w * 4 + q) * 512]); \
  } while (0)

  STAGE(0, 0);

#pragma unroll 1
  for (int t = 0; t < 64; ++t) {
    const int cur = t & 1;
    const short* qlc = ql[cur];
    const short* vlc = vl[cur];
    short* plc = pl[cur];

    asm volatile("s_waitcnt vmcnt(0)" ::: "memory");
    __builtin_amdgcn_s_barrier();  // (A) staging(t) ready everywhere; PV(t-1) retired
    if (t + 1 < 64) STAGE(cur ^ 1, t + 1);

    // ---- S' phase: S'[i,j] = e[i,j], lane holds col j fixed, rows i in regs ----
    f32x16 sacc[2] = {};
#pragma unroll
    for (int ks = 0; ks < 4; ++ks) {
      int gq = ks * 2 + hi;
      bf16x8 qf0 = *(const bf16x8*)(qlc + l31 * 64 + ((gq ^ (l31 & 7)) * 8));
      bf16x8 qf1 = *(const bf16x8*)(qlc + (32 + l31) * 64 + ((gq ^ ((32 + l31) & 7)) * 8));
      sacc[0] = mfma32(qf0, kf[ks], sacc[0]);
      sacc[1] = mfma32(qf1, kf[ks], sacc[1]);
    }
    // P = exp(S') -> bf16, packed 4-consecutive-i ds_write_b64 into pl[j][i]
    {
      const int jw = w * 32 + l31;
      short* prow = plc + jw * 64 + hi * 4;
#pragma unroll
      for (int f = 0; f < 2; ++f)
#pragma unroll
        for (int m = 0; m < 4; ++m) {
          bf16x4 s4;
#pragma unroll
          for (int s = 0; s < 4; ++s) s4[s] = f2bf(__expf(sacc[f][4 * m + s]));
          *(bf16x4*)(prow + (((4 * f + m) ^ (jw & 7)) * 8)) = s4;
        }
    }
    asm volatile("s_waitcnt lgkmcnt(0)" ::: "memory");
    __builtin_amdgcn_s_barrier();  // (B) pl[cur] visible; vmcnt stays in flight

    // ---- PV phase: O[c,j] += Vs[c,i] . P[j,i] ----
#pragma unroll
    for (int ks = 0; ks < 4; ++ks) {
      const int gk = ks * 2 + hi;
      bf16x8 vf[4], pf[2];
#pragma unroll
      for (int cf = 0; cf < 4; ++cf) {
        int row = wc * 128 + cf * 32 + l31;
        vf[cf] = *(const bf16x8*)(vlc + row * 64 + ((gk ^ (row & 7)) * 8));
      }
#pragma unroll
      for (int jf = 0; jf < 2; ++jf) {
        int row = wj * 64 + jf * 32 + l31;
        pf[jf] = *(const bf16x8*)(plc + row * 64 + ((gk ^ (row & 7)) * 8));
      }
#pragma unroll
      for (int cf = 0; cf < 4; ++cf)
#pragma unroll
        for (int jf = 0; jf < 2; ++jf)
          oacc[cf][jf] = mfma32(vf[cf], pf[jf], oacc[cf][jf]);
    }
  }
#undef STAGE

  // fused epilogue: out = gamma*O + x
  const float* xb = x + (long long)b * CCH * N_TOK;
  float* ob = out + (long long)b * CCH * N_TOK;
#pragma unroll
  for (int cf = 0; cf < 4; ++cf)
#pragma unroll
    for (int jf = 0; jf < 2; ++jf)
#pragma unroll
      for (int tt = 0; tt < 16; ++tt) {
        int c = c0 + wc * 128 + cf * 32 + ((tt & 3) + 8 * (tt >> 2) + 4 * hi);
        int j = j0 + wj * 64 + jf * 32 + l31;
        long long idx = (long long)c * N_TOK + j;
        ob[idx] = gamma * oacc[cf][jf][tt] + xb[idx];
      }
}

extern "C" void kernel_launch(void* const* d_in, const int* in_sizes, int n_in,
                              void* d_out, int out_size, void* d_ws, size_t ws_size,
                              hipStream_t stream) {
  const float* x     = (const float*)d_in[0];
  const float* wq    = (const float*)d_in[1];
  const float* bq    = (const float*)d_in[2];
  const float* wk    = (const float*)d_in[3];
  const float* bk    = (const float*)d_in[4];
  const float* wv    = (const float*)d_in[5];
  const float* bv    = (const float*)d_in[6];
  const float* gamma = (const float*)d_in[7];
  float* out = (float*)d_out;
  char* ws = (char*)d_ws;

  // workspace layout (bytes)
  short* xT     = (short*)(ws);                 // 8*4096*512*2  = 33554432
  short* qkT    = (short*)(ws + 33554432);      // 8*4096*128*2  =  8388608
  short* v_bf   = (short*)(ws + 41943040);      // 8*512*4096*2  = 33554432
  float* Zinv   = (float*)(ws + 75497472);      // 8*4096*4      =   131072
  short* wqk_bf = (short*)(ws + 75628544);      // 128*512*2     =   131072
  short* wv_bf  = (short*)(ws + 75759616);      // 512*512*2     =   524288
  float* bqk    = (float*)(ws + 76283904);      // 128*4         =      512

  k_conv_w<<<dim3(256), dim3(256), 0, stream>>>(wq, wk, wv, bq, bk, wqk_bf, wv_bf, bqk);
  k_transpose_x<<<dim3(64, 8, 8), dim3(256), 0, stream>>>(x, xT);
  // qkT[b,n,0:128] = xT[b,n,:] @ [wq;wk]^T + [bq;bk]
  k_gemm_nt<<<dim3(1, 32, 8), dim3(256), 0, stream>>>(
      xT, (long long)4096 * 512, wqk_bf, (long long)0,
      qkT, (long long)4096 * 128, 128, bqk, 0, nullptr, 0, 512);
  // Zinv[b,i] = 1 / sum_j exp(e[i,j])
  k_passA<<<dim3(64, 8), dim3(256), 0, stream>>>(qkT, Zinv);
  // v_bf[b,c,n] = (wv[c,:] @ xT[b,n,:] + bv[c]) * Zinv[b,n]
  k_gemm_nt<<<dim3(32, 4, 8), dim3(256), 0, stream>>>(
      wv_bf, (long long)0, xT, (long long)4096 * 512,
      v_bf, (long long)512 * 4096, 4096, bv, 1, Zinv, (long long)N_TOK, 512);
  k_passB<<<dim3(16, 2, 8), dim3(512), 0, stream>>>(qkT, v_bf, x, gamma, out);
}